// Round 2
// baseline (291.458 us; speedup 1.0000x reference)
//
#include <hip/hip_runtime.h>

typedef float v2f __attribute__((ext_vector_type(2)));

// ---- problem ----
// x:[4,16,8,64,64] f32, w_q/w_k/w_v:[64,8] f32, w_p:[2] f32
// out:[4,16,64,64,64] f32
// Attention batch B = bb*64 + o: q-side channel i (all 16) row o;
// k/v-side channel o>>2, w_k/w_v rows (o&3)*16+j; uk += 2*pe; scale 0.125
// folded into w_q (plus log2e when exp2 available); residual = mean over m;
// single-pass softmax (|logit| << 88): out = (sum_j e_j*uv_j)/(sum_j e_j).
//
// R12: revert to R10's high-concurrency shape (8192 blocks, 2 tiles, 2 i
// per thread) — R11 proved the kernel is latency-bound and lives on wave
// overlap (VALUBusy ~= waves/SIMD * 8%). Deltas vs R10:
//  - s_wk/s_wv dropped from LDS (per-thread j row loaded from global, L1):
//    LDS 21504 -> 20480 B = exactly 8 blocks/CU (was 7).
//  - __launch_bounds__(256,8) pins VGPR<=64 so the 8th block is legal.
//  - stage-1 staging as float4 (1 load/thread, was 2x v2f).
//  - exp -> v_exp_f32 with log2(e) folded into wq pre-scale; fast rcp.

#if __has_builtin(__builtin_amdgcn_exp2f)
  #define EXP_FN(x) __builtin_amdgcn_exp2f(x)
  #define QSCALE 0.18033688011112043f   // 0.125 * log2(e)
#else
  #define EXP_FN(x) __expf(x)
  #define QSCALE 0.125f
#endif
#if __has_builtin(__builtin_amdgcn_rcpf)
  #define RCP_FN(x) __builtin_amdgcn_rcpf(x)
#else
  #define RCP_FN(x) (1.0f/(x))
#endif

__global__ __launch_bounds__(256, 8) void adapt_attn(
    const float* __restrict__ x,  const float* __restrict__ wq,
    const float* __restrict__ wk, const float* __restrict__ wv,
    const float* __restrict__ wp, float* __restrict__ out)
{
    __shared__ __align__(16) v2f s_xk[2][8][2][16];   // 4 KB  [t][m][row][p]
    __shared__ float4 s_uk[2][16][16];                // 8 KB  [t][j][p]
    __shared__ float4 s_uv[2][16][16];                // 8 KB   -> 20480 total

    const int tid = threadIdx.x;          // 0..255
    const int bid = blockIdx.x;           // ((bb*64+o)*32)+tg ; 8192 blocks
    const int tg = bid & 31;
    const int o  = (bid >> 5) & 63;
    const int bb = bid >> 11;
    const int r = o & 3, qch = o >> 2;

    const v2f*    __restrict__ x2 = (const v2f*)x;    // v2f strides: m 2048, row 32
    const float4* __restrict__ x4 = (const float4*)x; // f4 strides: m 1024, row 16

    // ---- A: issue stage-1 k/v staging load (1 float4 per thread) ----
    float4 s1;
    {
        const int f = tid & 7, row = (tid >> 3) & 1, m = (tid >> 4) & 7, t = tid >> 7;
        const int tile = tg * 2 + t;
        const int y0 = (tile >> 1) << 1, w8 = (tile & 1) * 8;
        s1 = x4[((bb * 16 + qch) * 8 + m) * 1024 + (y0 + row) * 16 + w8 + f];
    }

    // ---- C: q loads + q-conv + residual (hides A latency) ----
    const int p3 = tid & 15, ig = (tid >> 4) & 7, t3 = tid >> 7;
    const int tile3 = tg * 2 + t3;
    const int y03 = (tile3 >> 1) << 1, ww03 = (tile3 & 1) << 4;
    const int sp = y03 * 32 + ww03 + p3;  // v2f offset within a 64x64 plane

    float wqr[8];
    #pragma unroll
    for (int m = 0; m < 8; m++)
        wqr[m] = QSCALE * wq[(o << 3) + m];          // uniform scalar loads

    v2f qa0[8], qb0[8], qa1[8], qb1[8];
    {
        const int bq0 = (bb * 16 + ig * 2) * 16384 + sp;
        const int bq1 = bq0 + 16384;
        #pragma unroll
        for (int m = 0; m < 8; m++) {                // lanes 0-15 coalesced 128B
            qa0[m] = x2[bq0 + m * 2048];
            qb0[m] = x2[bq0 + m * 2048 + 32];
            qa1[m] = x2[bq1 + m * 2048];
            qb1[m] = x2[bq1 + m * 2048 + 32];
        }
    }

    v2f uqa0 = {0.f,0.f}, uqb0 = {0.f,0.f}, rsa0 = {0.f,0.f}, rsb0 = {0.f,0.f};
    v2f uqa1 = {0.f,0.f}, uqb1 = {0.f,0.f}, rsa1 = {0.f,0.f}, rsb1 = {0.f,0.f};
    #pragma unroll
    for (int m = 0; m < 8; m++) {
        uqa0 += qa0[m] * wqr[m];          // wq pre-scaled (incl. log2e)
        uqb0 += qb0[m] * wqr[m];
        rsa0 += qa0[m];
        rsb0 += qb0[m];
        uqa1 += qa1[m] * wqr[m];
        uqb1 += qb1[m] * wqr[m];
        rsa1 += qa1[m];
        rsb1 += qb1[m];
    }

    // ---- D: LDS store for stage-1 tile ----
    {
        const int f = tid & 7, row = (tid >> 3) & 1, m = (tid >> 4) & 7, t = tid >> 7;
        *(float4*)&s_xk[t][m][row][f * 2] = s1;
    }

    // ---- B: stage-2 weights straight from global (L1-resident, 2 KB) ----
    const int p2 = tid & 15, j2 = (tid >> 4) & 15;   // per-thread j, both tiles
    float wkj[8], wvj[8];
    {
        const float4* wk4 = (const float4*)wk;
        const float4* wv4 = (const float4*)wv;
        const int rb = (r * 16 + j2) * 2;
        *(float4*)&wkj[0] = wk4[rb];   *(float4*)&wkj[4] = wk4[rb + 1];
        *(float4*)&wvj[0] = wv4[rb];   *(float4*)&wvj[4] = wv4[rb + 1];
    }
    const float wp0 = wp[0], wp1 = wp[1];
    __syncthreads();

    // ---- stage 2: build uk/uv[t][j2][p2] for both tiles ----
    const float step = 2.0f / 63.0f;
    #pragma unroll
    for (int t = 0; t < 2; t++) {
        const int tile = tg * 2 + t;
        const int y0 = (tile >> 1) << 1, ww0 = (tile & 1) << 4;
        const int wwp = ww0 + p2;
        const float lx0 = -1.0f + step * (float)(wwp << 1);
        const float lx1 = lx0 + step;
        const float ly0 = -1.0f + step * (float)y0;
        const float ly1 = ly0 + step;
        v2f ka = { 2.0f * (wp0 * lx0 + wp1 * ly0), 2.0f * (wp0 * lx1 + wp1 * ly0) };
        v2f kb = { 2.0f * (wp0 * lx0 + wp1 * ly1), 2.0f * (wp0 * lx1 + wp1 * ly1) };
        v2f va = {0.f, 0.f}, vb = {0.f, 0.f};

        #pragma unroll
        for (int m = 0; m < 8; m++) {
            const v2f xa = s_xk[t][m][0][p2];
            const v2f xb = s_xk[t][m][1][p2];
            ka += xa * wkj[m]; kb += xb * wkj[m];
            va += xa * wvj[m]; vb += xb * wvj[m];
        }
        s_uk[t][j2][p2] = make_float4(ka.x, ka.y, kb.x, kb.y);
        s_uv[t][j2][p2] = make_float4(va.x, va.y, vb.x, vb.y);
    }
    __syncthreads();

    // ---- stage 3: fused att + softmax + AV ----
    {
        v2f oa0 = {0.f, 0.f}, ob0 = {0.f, 0.f};
        v2f oa1 = {0.f, 0.f}, ob1 = {0.f, 0.f};
        float sum0 = 0.f, sum1 = 0.f;

        #pragma unroll
        for (int j = 0; j < 16; j++) {
            const float4 k4 = s_uk[t3][j][p3];    // 4-lane broadcast: free
            const float4 v4 = s_uv[t3][j][p3];
            const v2f ka = {k4.x, k4.y}, kb = {k4.z, k4.w};
            const v2f va = {v4.x, v4.y}, vb = {v4.z, v4.w};

            v2f t0 = uqa0 * ka;
            t0 += uqb0 * kb;
            const float e0 = EXP_FN(t0.x + t0.y);
            sum0 += e0;
            oa0 += va * e0;
            ob0 += vb * e0;

            v2f t1 = uqa1 * ka;
            t1 += uqb1 * kb;
            const float e1 = EXP_FN(t1.x + t1.y);
            sum1 += e1;
            oa1 += va * e1;
            ob1 += vb * e1;
        }

        v2f* __restrict__ out2 = (v2f*)out;
        {
            const int i = ig * 2;
            const float rcp = RCP_FN(sum0);
            const v2f outa = oa0 * rcp + rsa0 * 0.125f;   // residual = mean/m
            const v2f outb = ob0 * rcp + rsb0 * 0.125f;
            const int obi = ((bb * 16 + i) * 64 + o) * 2048 + sp;
            out2[obi]      = outa;    // row y03
            out2[obi + 32] = outb;    // row y03+1
        }
        {
            const int i = ig * 2 + 1;
            const float rcp = RCP_FN(sum1);
            const v2f outa = oa1 * rcp + rsa1 * 0.125f;
            const v2f outb = ob1 * rcp + rsb1 * 0.125f;
            const int obi = ((bb * 16 + i) * 64 + o) * 2048 + sp;
            out2[obi]      = outa;
            out2[obi + 32] = outb;
        }
    }
}

extern "C" void kernel_launch(void* const* d_in, const int* in_sizes, int n_in,
                              void* d_out, int out_size, void* d_ws, size_t ws_size,
                              hipStream_t stream) {
    const float* x  = (const float*)d_in[0];
    const float* wq = (const float*)d_in[1];
    const float* wk = (const float*)d_in[2];
    const float* wv = (const float*)d_in[3];
    const float* wp = (const float*)d_in[4];
    float* out = (float*)d_out;
    // 4 bb * 64 o * 32 tile-pairs = 8192 blocks of 256 threads
    adapt_attn<<<dim3(8192), dim3(256), 0, stream>>>(x, wq, wk, wv, wp, out);
}

// Round 3
// 118.237 us; speedup vs baseline: 2.4650x; 2.4650x over previous
//
#include <hip/hip_runtime.h>

typedef float v2f __attribute__((ext_vector_type(2)));

// ---- problem ----
// x:[4,16,8,64,64] f32, w_q/w_k/w_v:[64,8] f32, w_p:[2] f32
// out:[4,16,64,64,64] f32
// Attention batch B = bb*64 + o: q-side channel i (all 16) row o;
// k/v-side channel o>>2, w_k/w_v rows (o&3)*16+j; uk += 2*pe; scale 0.125
// folded into w_q (plus log2e when exp2 available); residual = mean over m;
// single-pass softmax (|logit| << 88): out = (sum_j e_j*uv_j)/(sum_j e_j).
//
// R13 = R12 structure with __launch_bounds__(256,4). R12's (256,8) pinned
// the allocator to 32 VGPRs -> massive scratch spill (FETCH 4.2->296 MB,
// WRITE 65->573 MB, 234 us). At (256,4) the kernel compiles spill-free
// (~56-64 VGPR, proven in R10/R11); LDS=20480 B still admits 8 blocks/CU
// and VGPR<=64 admits 8 waves/SIMD, so HW occupancy cap is unchanged —
// just without buying it with spills.
//  - s_wk/s_wv dropped from LDS (per-thread j row from global, L1-resident)
//  - stage-1 staging as float4 (1 load/thread)
//  - exp -> v_exp_f32 with log2(e) folded into wq pre-scale; fast rcp

#if __has_builtin(__builtin_amdgcn_exp2f)
  #define EXP_FN(x) __builtin_amdgcn_exp2f(x)
  #define QSCALE 0.18033688011112043f   // 0.125 * log2(e)
#else
  #define EXP_FN(x) __expf(x)
  #define QSCALE 0.125f
#endif
#if __has_builtin(__builtin_amdgcn_rcpf)
  #define RCP_FN(x) __builtin_amdgcn_rcpf(x)
#else
  #define RCP_FN(x) (1.0f/(x))
#endif

__global__ __launch_bounds__(256, 4) void adapt_attn(
    const float* __restrict__ x,  const float* __restrict__ wq,
    const float* __restrict__ wk, const float* __restrict__ wv,
    const float* __restrict__ wp, float* __restrict__ out)
{
    __shared__ __align__(16) v2f s_xk[2][8][2][16];   // 4 KB  [t][m][row][p]
    __shared__ float4 s_uk[2][16][16];                // 8 KB  [t][j][p]
    __shared__ float4 s_uv[2][16][16];                // 8 KB   -> 20480 total

    const int tid = threadIdx.x;          // 0..255
    const int bid = blockIdx.x;           // ((bb*64+o)*32)+tg ; 8192 blocks
    const int tg = bid & 31;
    const int o  = (bid >> 5) & 63;
    const int bb = bid >> 11;
    const int r = o & 3, qch = o >> 2;

    const v2f*    __restrict__ x2 = (const v2f*)x;    // v2f strides: m 2048, row 32
    const float4* __restrict__ x4 = (const float4*)x; // f4 strides: m 1024, row 16

    // ---- A: issue stage-1 k/v staging load (1 float4 per thread) ----
    float4 s1;
    {
        const int f = tid & 7, row = (tid >> 3) & 1, m = (tid >> 4) & 7, t = tid >> 7;
        const int tile = tg * 2 + t;
        const int y0 = (tile >> 1) << 1, w8 = (tile & 1) * 8;
        s1 = x4[((bb * 16 + qch) * 8 + m) * 1024 + (y0 + row) * 16 + w8 + f];
    }

    // ---- C: q loads + q-conv + residual (hides A latency) ----
    const int p3 = tid & 15, ig = (tid >> 4) & 7, t3 = tid >> 7;
    const int tile3 = tg * 2 + t3;
    const int y03 = (tile3 >> 1) << 1, ww03 = (tile3 & 1) << 4;
    const int sp = y03 * 32 + ww03 + p3;  // v2f offset within a 64x64 plane

    float wqr[8];
    #pragma unroll
    for (int m = 0; m < 8; m++)
        wqr[m] = QSCALE * wq[(o << 3) + m];          // uniform scalar loads

    v2f qa0[8], qb0[8], qa1[8], qb1[8];
    {
        const int bq0 = (bb * 16 + ig * 2) * 16384 + sp;
        const int bq1 = bq0 + 16384;
        #pragma unroll
        for (int m = 0; m < 8; m++) {                // lanes 0-15 coalesced 128B
            qa0[m] = x2[bq0 + m * 2048];
            qb0[m] = x2[bq0 + m * 2048 + 32];
            qa1[m] = x2[bq1 + m * 2048];
            qb1[m] = x2[bq1 + m * 2048 + 32];
        }
    }

    v2f uqa0 = {0.f,0.f}, uqb0 = {0.f,0.f}, rsa0 = {0.f,0.f}, rsb0 = {0.f,0.f};
    v2f uqa1 = {0.f,0.f}, uqb1 = {0.f,0.f}, rsa1 = {0.f,0.f}, rsb1 = {0.f,0.f};
    #pragma unroll
    for (int m = 0; m < 8; m++) {
        uqa0 += qa0[m] * wqr[m];          // wq pre-scaled (incl. log2e)
        uqb0 += qb0[m] * wqr[m];
        rsa0 += qa0[m];
        rsb0 += qb0[m];
        uqa1 += qa1[m] * wqr[m];
        uqb1 += qb1[m] * wqr[m];
        rsa1 += qa1[m];
        rsb1 += qb1[m];
    }

    // ---- D: LDS store for stage-1 tile ----
    {
        const int f = tid & 7, row = (tid >> 3) & 1, m = (tid >> 4) & 7, t = tid >> 7;
        *(float4*)&s_xk[t][m][row][f * 2] = s1;
    }

    // ---- B: stage-2 weights straight from global (L1-resident, 2 KB) ----
    const int p2 = tid & 15, j2 = (tid >> 4) & 15;   // per-thread j, both tiles
    float wkj[8], wvj[8];
    {
        const float4* wk4 = (const float4*)wk;
        const float4* wv4 = (const float4*)wv;
        const int rb = (r * 16 + j2) * 2;
        *(float4*)&wkj[0] = wk4[rb];   *(float4*)&wkj[4] = wk4[rb + 1];
        *(float4*)&wvj[0] = wv4[rb];   *(float4*)&wvj[4] = wv4[rb + 1];
    }
    const float wp0 = wp[0], wp1 = wp[1];
    __syncthreads();

    // ---- stage 2: build uk/uv[t][j2][p2] for both tiles ----
    const float step = 2.0f / 63.0f;
    #pragma unroll
    for (int t = 0; t < 2; t++) {
        const int tile = tg * 2 + t;
        const int y0 = (tile >> 1) << 1, ww0 = (tile & 1) << 4;
        const int wwp = ww0 + p2;
        const float lx0 = -1.0f + step * (float)(wwp << 1);
        const float lx1 = lx0 + step;
        const float ly0 = -1.0f + step * (float)y0;
        const float ly1 = ly0 + step;
        v2f ka = { 2.0f * (wp0 * lx0 + wp1 * ly0), 2.0f * (wp0 * lx1 + wp1 * ly0) };
        v2f kb = { 2.0f * (wp0 * lx0 + wp1 * ly1), 2.0f * (wp0 * lx1 + wp1 * ly1) };
        v2f va = {0.f, 0.f}, vb = {0.f, 0.f};

        #pragma unroll
        for (int m = 0; m < 8; m++) {
            const v2f xa = s_xk[t][m][0][p2];
            const v2f xb = s_xk[t][m][1][p2];
            ka += xa * wkj[m]; kb += xb * wkj[m];
            va += xa * wvj[m]; vb += xb * wvj[m];
        }
        s_uk[t][j2][p2] = make_float4(ka.x, ka.y, kb.x, kb.y);
        s_uv[t][j2][p2] = make_float4(va.x, va.y, vb.x, vb.y);
    }
    __syncthreads();

    // ---- stage 3: fused att + softmax + AV ----
    {
        v2f oa0 = {0.f, 0.f}, ob0 = {0.f, 0.f};
        v2f oa1 = {0.f, 0.f}, ob1 = {0.f, 0.f};
        float sum0 = 0.f, sum1 = 0.f;

        #pragma unroll
        for (int j = 0; j < 16; j++) {
            const float4 k4 = s_uk[t3][j][p3];    // 4-lane broadcast: free
            const float4 v4 = s_uv[t3][j][p3];
            const v2f ka = {k4.x, k4.y}, kb = {k4.z, k4.w};
            const v2f va = {v4.x, v4.y}, vb = {v4.z, v4.w};

            v2f t0 = uqa0 * ka;
            t0 += uqb0 * kb;
            const float e0 = EXP_FN(t0.x + t0.y);
            sum0 += e0;
            oa0 += va * e0;
            ob0 += vb * e0;

            v2f t1 = uqa1 * ka;
            t1 += uqb1 * kb;
            const float e1 = EXP_FN(t1.x + t1.y);
            sum1 += e1;
            oa1 += va * e1;
            ob1 += vb * e1;
        }

        v2f* __restrict__ out2 = (v2f*)out;
        {
            const int i = ig * 2;
            const float rcp = RCP_FN(sum0);
            const v2f outa = oa0 * rcp + rsa0 * 0.125f;   // residual = mean/m
            const v2f outb = ob0 * rcp + rsb0 * 0.125f;
            const int obi = ((bb * 16 + i) * 64 + o) * 2048 + sp;
            out2[obi]      = outa;    // row y03
            out2[obi + 32] = outb;    // row y03+1
        }
        {
            const int i = ig * 2 + 1;
            const float rcp = RCP_FN(sum1);
            const v2f outa = oa1 * rcp + rsa1 * 0.125f;
            const v2f outb = ob1 * rcp + rsb1 * 0.125f;
            const int obi = ((bb * 16 + i) * 64 + o) * 2048 + sp;
            out2[obi]      = outa;
            out2[obi + 32] = outb;
        }
    }
}

extern "C" void kernel_launch(void* const* d_in, const int* in_sizes, int n_in,
                              void* d_out, int out_size, void* d_ws, size_t ws_size,
                              hipStream_t stream) {
    const float* x  = (const float*)d_in[0];
    const float* wq = (const float*)d_in[1];
    const float* wk = (const float*)d_in[2];
    const float* wv = (const float*)d_in[3];
    const float* wp = (const float*)d_in[4];
    float* out = (float*)d_out;
    // 4 bb * 64 o * 32 tile-pairs = 8192 blocks of 256 threads
    adapt_attn<<<dim3(8192), dim3(256), 0, stream>>>(x, wq, wk, wv, wp, out);
}